// Round 1
// baseline (189.007 us; speedup 1.0000x reference)
//
#include <hip/hip_runtime.h>

#define NUM_LABELS 500
#define NB 8
#define NP (1024 * 1024)
#define BPB 128   // blocks per batch
#define TPB 512
#define NBLK (NB * BPB)

// Per-block packed u64 fixed-point accumulator per label:
//   bits [48..63] : count of pixels
//   bits [24..47] : sum of round((v+64)*256), v = sum of 3 channel values
//   bits [0 ..23] : sum of round(q*64), q = sum of 3 channel squares
// One ds_add_u64 per pixel; per-block partials streamed to global (no pre-zero,
// no global atomics, no memset dispatch).

__device__ __forceinline__ void lv_accum(unsigned long long* h, int t,
                                         float a, float b, float c) {
    if (t > 0) {
        float v = a + b + c;
        float q = a * a + b * b + c * c;
        unsigned vf = (unsigned)(fmaf(v, 256.f, 16384.5f));  // (v+64)*256, rounded
        unsigned qf = (unsigned)(fmaf(q, 64.f, 0.5f));       // q*64, rounded
        unsigned long long pk =
            (1ULL << 48) | ((unsigned long long)vf << 24) | (unsigned long long)qf;
        atomicAdd(&h[t], pk);
    }
}

__global__ __launch_bounds__(TPB) void lv_bins(const float* __restrict__ x,
                                               const int* __restrict__ tgt,
                                               unsigned long long* __restrict__ part,
                                               unsigned int* __restrict__ counter) {
    // 2 histogram copies: even waves use h[0..499], odd waves h[500..999].
    __shared__ unsigned long long h[2 * NUM_LABELS];

    const int b = blockIdx.y;

    // Re-zero the done-counter for lv_final (stream order makes this safe).
    if (threadIdx.x == 0 && blockIdx.x == 0 && b == 0) atomicExch(counter, 0u);

    for (int i = threadIdx.x; i < 2 * NUM_LABELS; i += TPB) h[i] = 0ULL;
    __syncthreads();

    unsigned long long* hw = h + ((threadIdx.x >> 6) & 1) * NUM_LABELS;

    const float* x0 = x + (size_t)(b * 3 + 0) * NP;
    const float* x1 = x + (size_t)(b * 3 + 1) * NP;
    const float* x2 = x + (size_t)(b * 3 + 2) * NP;
    const int*   tg = tgt + (size_t)b * NP;

    const int pixPerBlock = NP / BPB;           // 8192
    const int stride = TPB * 4;                 // 2048
    const int nIter = pixPerBlock / stride;     // 4

    int p = blockIdx.x * pixPerBlock + (int)threadIdx.x * 4;

    // software-pipelined: next iteration's loads issue before current atomics
    int4   t4 = *(const int4*)(tg + p);
    float4 a4 = *(const float4*)(x0 + p);
    float4 b4 = *(const float4*)(x1 + p);
    float4 c4 = *(const float4*)(x2 + p);

    for (int it = 0; it < nIter - 1; ++it) {
        const int pn = p + stride;
        int4   tn = *(const int4*)(tg + pn);
        float4 an = *(const float4*)(x0 + pn);
        float4 bn = *(const float4*)(x1 + pn);
        float4 cn = *(const float4*)(x2 + pn);

        lv_accum(hw, t4.x, a4.x, b4.x, c4.x);
        lv_accum(hw, t4.y, a4.y, b4.y, c4.y);
        lv_accum(hw, t4.z, a4.z, b4.z, c4.z);
        lv_accum(hw, t4.w, a4.w, b4.w, c4.w);

        t4 = tn; a4 = an; b4 = bn; c4 = cn;
        p = pn;
    }
    lv_accum(hw, t4.x, a4.x, b4.x, c4.x);
    lv_accum(hw, t4.y, a4.y, b4.y, c4.y);
    lv_accum(hw, t4.z, a4.z, b4.z, c4.z);
    lv_accum(hw, t4.w, a4.w, b4.w, c4.w);

    __syncthreads();

    // Merge the 2 copies and stream the block's partial histogram to global.
    // Unconditional store: the buffer is NOT pre-zeroed.
    unsigned long long* dst = part + (size_t)(b * BPB + blockIdx.x) * NUM_LABELS;
    for (int i = threadIdx.x; i < NUM_LABELS; i += TPB)
        dst[i] = h[i] + h[NUM_LABELS + i];
}

// Finalize: 8 blocks, block b reduces batch b's 128 partials over labels 1..499.
// Last-done block combines the 8 per-batch terms (device-scope atomics for
// cross-XCD visibility) — no third dispatch, no zeroed output needed.
__global__ __launch_bounds__(512) void lv_final(const unsigned long long* __restrict__ part,
                                                float* __restrict__ terms,
                                                unsigned int* __restrict__ counter,
                                                float* __restrict__ out) {
    const int b = blockIdx.x;
    const int l = threadIdx.x;

    float cnt = 0.f, sv = 0.f, sq = 0.f;
    if (l >= 1 && l < NUM_LABELS) {
        const unsigned long long* pp = part + (size_t)b * BPB * NUM_LABELS + l;
#pragma unroll 4
        for (int blk = 0; blk < BPB; ++blk) {
            unsigned long long w = pp[(size_t)blk * NUM_LABELS];
            float c = (float)(unsigned)(w >> 48);
            cnt += c;
            sv  += (float)(unsigned)((w >> 24) & 0xFFFFFFu) * (1.f / 256.f) - 64.f * c;
            sq  += (float)(unsigned)(w & 0xFFFFFFu) * (1.f / 64.f);
        }
    }

    float uniq = (cnt > 0.f) ? 1.f : 0.f;
    float var = 0.f;
    if (cnt > 1.f) {
        float N = 3.f * cnt;
        var = (sq - sv * sv / N) / (N - 1.f);
    }

    for (int off = 32; off > 0; off >>= 1) {
        var  += __shfl_down(var, off);
        uniq += __shfl_down(uniq, off);
    }

    __shared__ float wv[8], wu[8];
    const int wave = threadIdx.x >> 6;
    const int lane = threadIdx.x & 63;
    if (lane == 0) { wv[wave] = var; wu[wave] = uniq; }
    __syncthreads();

    if (threadIdx.x == 0) {
        float V = 0.f, U = 0.f;
        for (int i = 0; i < 8; ++i) { V += wv[i]; U += wu[i]; }
        atomicExch(&terms[b], V / (U + 1e-8f));   // device-scope write
        __threadfence();
        unsigned old = atomicAdd(counter, 1u);
        if (old == NB - 1) {
            float acc = 0.f;
            for (int i = 0; i < NB; ++i) acc += atomicAdd(&terms[i], 0.f);  // coherent read
            out[0] = acc * (1.f / NB);
        }
    }
}

extern "C" void kernel_launch(void* const* d_in, const int* in_sizes, int n_in,
                              void* d_out, int out_size, void* d_ws, size_t ws_size,
                              hipStream_t stream) {
    const float* x   = (const float*)d_in[0];
    const int*   tgt = (const int*)d_in[1];
    float*       out = (float*)d_out;

    // ws layout: [ partials: 1024*500 u64 = 4,096,000 B ][ terms: 8 f32 ][ counter: u32 ]
    unsigned long long* part = (unsigned long long*)d_ws;
    float* terms = (float*)((char*)d_ws + (size_t)NBLK * NUM_LABELS * 8);
    unsigned int* counter =
        (unsigned int*)((char*)d_ws + (size_t)NBLK * NUM_LABELS * 8 + 8 * sizeof(float));

    dim3 grid(BPB, NB);
    lv_bins<<<grid, TPB, 0, stream>>>(x, tgt, part, counter);
    lv_final<<<NB, 512, 0, stream>>>(part, terms, counter, out);
}

// Round 2
// 185.335 us; speedup vs baseline: 1.0198x; 1.0198x over previous
//
#include <hip/hip_runtime.h>

#define NUM_LABELS 500
#define NB 8
#define NP (1024 * 1024)
#define BPB 128   // blocks per batch
#define TPB 512
#define NBLK (NB * BPB)

// Per-block packed u64 fixed-point accumulator per label:
//   bits [48..63] : count of pixels
//   bits [24..47] : sum of round((v+64)*256), v = sum of 3 channel values
//   bits [0 ..23] : sum of round(q*64), q = sum of 3 channel squares
// One ds_add_u64 per pixel; per-block partials streamed to global (no pre-zero,
// no global atomics, no memset dispatch).

__device__ __forceinline__ void lv_accum(unsigned long long* h, int t,
                                         float a, float b, float c) {
    // Branchless: label-0 pixels land in h[0], which finalize ignores
    // (reference drops label 0). Saves a cmp+exec-mask per pixel.
    float v = a + b + c;
    float q = a * a + b * b + c * c;
    unsigned vf = (unsigned)(fmaf(v, 256.f, 16384.5f));  // (v+64)*256, rounded
    unsigned qf = (unsigned)(fmaf(q, 64.f, 0.5f));       // q*64, rounded
    unsigned long long pk =
        (1ULL << 48) | ((unsigned long long)vf << 24) | (unsigned long long)qf;
    atomicAdd(&h[t], pk);
}

__global__ __launch_bounds__(TPB) void lv_bins(const float* __restrict__ x,
                                               const int* __restrict__ tgt,
                                               unsigned long long* __restrict__ part,
                                               unsigned int* __restrict__ counter) {
    // 2 histogram copies: even waves use h[0..499], odd waves h[500..999].
    __shared__ unsigned long long h[2 * NUM_LABELS];

    const int b = blockIdx.y;

    // Re-zero the done-counter for lv_final (stream order makes this safe:
    // lv_final is a later dispatch on the same stream).
    if (threadIdx.x == 0 && blockIdx.x == 0 && b == 0) atomicExch(counter, 0u);

    for (int i = threadIdx.x; i < 2 * NUM_LABELS; i += TPB) h[i] = 0ULL;
    __syncthreads();

    unsigned long long* hw = h + ((threadIdx.x >> 6) & 1) * NUM_LABELS;

    const float* x0 = x + (size_t)(b * 3 + 0) * NP;
    const float* x1 = x + (size_t)(b * 3 + 1) * NP;
    const float* x2 = x + (size_t)(b * 3 + 2) * NP;
    const int*   tg = tgt + (size_t)b * NP;

    const int pixPerBlock = NP / BPB;           // 8192
    const int stride = TPB * 4;                 // 2048
    const int nIter = pixPerBlock / stride;     // 4

    int p = blockIdx.x * pixPerBlock + (int)threadIdx.x * 4;

    // software-pipelined: next iteration's loads issue before current atomics
    int4   t4 = *(const int4*)(tg + p);
    float4 a4 = *(const float4*)(x0 + p);
    float4 b4 = *(const float4*)(x1 + p);
    float4 c4 = *(const float4*)(x2 + p);

    for (int it = 0; it < nIter - 1; ++it) {
        const int pn = p + stride;
        int4   tn = *(const int4*)(tg + pn);
        float4 an = *(const float4*)(x0 + pn);
        float4 bn = *(const float4*)(x1 + pn);
        float4 cn = *(const float4*)(x2 + pn);

        lv_accum(hw, t4.x, a4.x, b4.x, c4.x);
        lv_accum(hw, t4.y, a4.y, b4.y, c4.y);
        lv_accum(hw, t4.z, a4.z, b4.z, c4.z);
        lv_accum(hw, t4.w, a4.w, b4.w, c4.w);

        t4 = tn; a4 = an; b4 = bn; c4 = cn;
        p = pn;
    }
    lv_accum(hw, t4.x, a4.x, b4.x, c4.x);
    lv_accum(hw, t4.y, a4.y, b4.y, c4.y);
    lv_accum(hw, t4.z, a4.z, b4.z, c4.z);
    lv_accum(hw, t4.w, a4.w, b4.w, c4.w);

    __syncthreads();

    // Merge the 2 copies and stream the block's partial histogram to global.
    // Unconditional store: the buffer is NOT pre-zeroed.
    unsigned long long* dst = part + (size_t)(b * BPB + blockIdx.x) * NUM_LABELS;
    for (int i = threadIdx.x; i < NUM_LABELS; i += TPB)
        dst[i] = h[i] + h[NUM_LABELS + i];
}

// Finalize: 8 blocks, block b reduces batch b's 128 partials over labels 1..499.
// unroll 16 → 16 outstanding loads/thread: ~8 latency rounds instead of 32.
__global__ __launch_bounds__(512) void lv_final(const unsigned long long* __restrict__ part,
                                                float* __restrict__ terms,
                                                unsigned int* __restrict__ counter,
                                                float* __restrict__ out) {
    const int b = blockIdx.x;
    const int l = threadIdx.x;

    float cnt = 0.f, sv = 0.f, sq = 0.f;
    if (l >= 1 && l < NUM_LABELS) {
        const unsigned long long* pp = part + (size_t)b * BPB * NUM_LABELS + l;
#pragma unroll 16
        for (int blk = 0; blk < BPB; ++blk) {
            unsigned long long w = pp[(size_t)blk * NUM_LABELS];
            float c = (float)(unsigned)(w >> 48);
            cnt += c;
            sv  += (float)(unsigned)((w >> 24) & 0xFFFFFFu) * (1.f / 256.f) - 64.f * c;
            sq  += (float)(unsigned)(w & 0xFFFFFFu) * (1.f / 64.f);
        }
    }

    float uniq = (cnt > 0.f) ? 1.f : 0.f;
    float var = 0.f;
    if (cnt > 1.f) {
        float N = 3.f * cnt;
        var = (sq - sv * sv / N) / (N - 1.f);
    }

    for (int off = 32; off > 0; off >>= 1) {
        var  += __shfl_down(var, off);
        uniq += __shfl_down(uniq, off);
    }

    __shared__ float wv[8], wu[8];
    const int wave = threadIdx.x >> 6;
    const int lane = threadIdx.x & 63;
    if (lane == 0) { wv[wave] = var; wu[wave] = uniq; }
    __syncthreads();

    if (threadIdx.x == 0) {
        float V = 0.f, U = 0.f;
        for (int i = 0; i < 8; ++i) { V += wv[i]; U += wu[i]; }
        atomicExch(&terms[b], V / (U + 1e-8f));   // device-scope write
        __threadfence();
        unsigned old = atomicAdd(counter, 1u);
        if (old == NB - 1) {
            float acc = 0.f;
            for (int i = 0; i < NB; ++i) acc += atomicAdd(&terms[i], 0.f);  // coherent read
            out[0] = acc * (1.f / NB);
        }
    }
}

extern "C" void kernel_launch(void* const* d_in, const int* in_sizes, int n_in,
                              void* d_out, int out_size, void* d_ws, size_t ws_size,
                              hipStream_t stream) {
    const float* x   = (const float*)d_in[0];
    const int*   tgt = (const int*)d_in[1];
    float*       out = (float*)d_out;

    // ws layout: [ partials: 1024*500 u64 = 4,096,000 B ][ terms: 8 f32 ][ counter: u32 ]
    unsigned long long* part = (unsigned long long*)d_ws;
    float* terms = (float*)((char*)d_ws + (size_t)NBLK * NUM_LABELS * 8);
    unsigned int* counter =
        (unsigned int*)((char*)d_ws + (size_t)NBLK * NUM_LABELS * 8 + 8 * sizeof(float));

    dim3 grid(BPB, NB);
    lv_bins<<<grid, TPB, 0, stream>>>(x, tgt, part, counter);
    lv_final<<<NB, 512, 0, stream>>>(part, terms, counter, out);
}